// Round 21
// baseline (108.853 us; speedup 1.0000x reference)
//
#include <hip/hip_runtime.h>

typedef _Float16 half2v __attribute__((ext_vector_type(2)));
typedef _Float16 half4v __attribute__((ext_vector_type(4)));
typedef _Float16 half8v __attribute__((ext_vector_type(8)));

#define HH 1024
#define OHW 256
#define TH 16
#define TW 64
#define NR 80        // input-tile rows
#define NCH 34       // data chunks (8 halves) per row = 272 cols
#define ROWH 288     // padded row stride in halves (36 chunks)
#define NTHREADS 256
#define ESPAN 528    // edge strip length (halves/floats)

#define NMAIN 2048           // 4 x 16 x 32 main blocks
#define NEDGE 384            // 2 x 6 x 32
#define NCORN 288            // 3 x 3 x 32
#define NAUX  (NEDGE + NCORN)

#if defined(__has_builtin)
#  if __has_builtin(__builtin_amdgcn_fdot2)
#    define HAS_FDOT2 1
#  endif
#endif
#ifndef HAS_FDOT2
#  define HAS_FDOT2 0
#endif

__constant__ float DEC12c[12] = {
  -1.20162964e-04f,  1.615524292e-03f, -1.0385513306e-02f,  4.3619155884e-02f,
  -1.45397186478e-01f, 6.10668182370e-01f, 6.10668182370e-01f, -1.45397186478e-01f,
   4.3619155884e-02f, -1.0385513306e-02f,  1.615524292e-03f, -1.20162964e-04f
};

__device__ __forceinline__ int clampi(int v) { return v < 0 ? 0 : (v > HH - 1 ? HH - 1 : v); }

__device__ __forceinline__ int swzc(int c, int r) {
  return c ^ ((c >> 3) & 1) ^ ((r >> 2) & 3);
}

__device__ __forceinline__ half2v mk2(_Float16 a, _Float16 b) {
  half2v r; r.x = a; r.y = b; return r;
}

template<int J>   // J = half2 index 0..15 within 4 half8 regs
__device__ __forceinline__ half2v sel4(half8v a, half8v b, half8v c, half8v d) {
  constexpr int V = J >> 2, E = J & 3;
  const half8v s = (V == 0) ? a : (V == 1) ? b : (V == 2) ? c : d;
  return mk2(s[2 * E], s[2 * E + 1]);
}
template<int E>
__device__ __forceinline__ half2v g2(half8v v) { return mk2(v[2 * E], v[2 * E + 1]); }

__device__ __forceinline__ float dot2acc(half2v w, half2v k, float acc) {
#if HAS_FDOT2
  return __builtin_amdgcn_fdot2(w, k, acc, false);
#else
  return acc + (float)w.x * (float)k.x + (float)w.y * (float)k.y;
#endif
}

// ---------------- dispatch 1: per-image combined 20x20 kernel -> d_ws (f16) ----------------
__global__ __launch_bounds__(128) void dgp_ckbuild(
    const float* __restrict__ mtfp, const int* __restrict__ rp,
    const int* __restrict__ cp, _Float16* __restrict__ ckg) {
  __shared__ float kva[180];
  __shared__ float mlds[81];
  __shared__ float avs[12], bvs[12];
  const int tid = threadIdx.x;
  const int bz = blockIdx.x;
  const int chC = bz & 7;
  const int rv = rp[bz], cv = cp[bz];
  const int rf = rv & 1, cf = cv & 1;

  if (tid < 12)       avs[tid] = rf ? DEC12c[tid] : (tid == 6 ? 1.f : 0.f);
  else if (tid < 24)  bvs[tid - 12] = cf ? DEC12c[tid - 12] : (tid - 12 == 6 ? 1.f : 0.f);
  else if (tid < 105) { const int m = tid - 24; mlds[m] = mtfp[m * 8 + chC]; }
  __syncthreads();

  for (int i = tid; i < 180; i += 128) {
    const int S = i / 9, v = i - S * 9;
    const int plo = (S - 8 > 0) ? S - 8 : 0, phi = (S < 11) ? S : 11;
    float s1 = 0.f;
    for (int p = plo; p <= phi; ++p) s1 += avs[p] * mlds[(S - p) * 9 + v];
    kva[i] = s1;
  }
  __syncthreads();

  half2v* out2 = (half2v*)ckg;
  for (int i = tid; i < 200; i += 128) {
    const int S = i / 10, m = i - S * 10;
    float s[2];
    #pragma unroll
    for (int h = 0; h < 2; ++h) {
      const int T = 2 * m + h;
      const int qlo = (T - 8 > 0) ? T - 8 : 0, qhi = (T < 11) ? T : 11;
      float acc = 0.f;
      for (int q = qlo; q <= qhi; ++q) acc += bvs[q] * kva[S * 9 + (T - q)];
      s[h] = acc;
    }
    out2[bz * 320 + S * 16 + m] = mk2((_Float16)s[0], (_Float16)s[1]);
  }
}

// ---------------- dispatch 2: fused edge + corner + main (aux FIRST) ----------------
// blocks [0,384): edge segments; [384,672): corners; [672,2720): main tiles.
// Disjoint write sets (main dump-redirects boundary; edge skips corners).
__global__ __launch_bounds__(NTHREADS) void dgp_fused(
    const float* __restrict__ inp, const float* __restrict__ mtfp,
    const int* __restrict__ rp, const int* __restrict__ cp,
    const _Float16* __restrict__ ckg, float* __restrict__ outg,
    float* __restrict__ dumpf) {
  __shared__ __align__(64) unsigned char smem[46080];
  const int tid = threadIdx.x;
  const int b = blockIdx.x;

  if (b >= NAUX) {
    // ================= main path: TW=64, 4 outputs/thread =================
    _Float16* tile = (_Float16*)smem;   // 80*288 halves = 46080 B
    const int bm = b - NAUX;
    const int bxt = bm & 3, by = (bm >> 2) & 15, bz = bm >> 6;
    const int rv = rp[bz], cv = cp[bz];
    const int ri = rv >> 1, ci = cv >> 1;
    const int R0 = 4 * TH * by - 8 - ri;
    const int C0 = 4 * TW * bxt - 8 - ci;

    const float* src = inp + ((size_t)bz << 20);
    for (int idx = tid; idx < NR * NCH; idx += NTHREADS) {
      const int rr = idx / 34, g = idx - 34 * rr;
      const float* grow = src + (clampi(R0 + rr) << 10);
      const int c0 = C0 + 8 * g;
      float v[8];
      if (c0 >= 0 && c0 + 7 <= HH - 1) {
        __builtin_memcpy(v, grow + c0, 32);
      } else {
        #pragma unroll
        for (int i = 0; i < 8; ++i) v[i] = grow[clampi(c0 + i)];
      }
      _Float16 h[8];
      #pragma unroll
      for (int i = 0; i < 8; ++i) h[i] = (_Float16)v[i];
      __builtin_memcpy(tile + rr * ROWH + (swzc(g, rr) << 3), h, 16);
    }
    __syncthreads();

    const int ty = tid >> 4;   // 0..15 output row
    const int tx = tid & 15;   // 0..15 -> 4 outputs at cols 4tx..4tx+3
    const int rbase = 4 * ty;
    const size_t kbase = (size_t)bz * 640;

    float s0e = 0.f, s0o = 0.f, s1e = 0.f, s1o = 0.f;
    float s2e = 0.f, s2o = 0.f, s3e = 0.f, s3o = 0.f;

// output m taps: half2 J = 2m + j, kernel half2 j (j=0..9)
#define OUTM(m, Ae, Ao, w0, w1, w2, w3, K0, K1, K2)                      \
    Ae = dot2acc(sel4<2*(m) + 0>(w0, w1, w2, w3), g2<0>(K0), Ae);        \
    Ao = dot2acc(sel4<2*(m) + 1>(w0, w1, w2, w3), g2<1>(K0), Ao);        \
    Ae = dot2acc(sel4<2*(m) + 2>(w0, w1, w2, w3), g2<2>(K0), Ae);        \
    Ao = dot2acc(sel4<2*(m) + 3>(w0, w1, w2, w3), g2<3>(K0), Ao);        \
    Ae = dot2acc(sel4<2*(m) + 4>(w0, w1, w2, w3), g2<0>(K1), Ae);        \
    Ao = dot2acc(sel4<2*(m) + 5>(w0, w1, w2, w3), g2<1>(K1), Ao);        \
    Ae = dot2acc(sel4<2*(m) + 6>(w0, w1, w2, w3), g2<2>(K1), Ae);        \
    Ao = dot2acc(sel4<2*(m) + 7>(w0, w1, w2, w3), g2<3>(K1), Ao);        \
    Ae = dot2acc(sel4<2*(m) + 8>(w0, w1, w2, w3), mk2(K2[0], K2[1]), Ae);\
    Ao = dot2acc(sel4<2*(m) + 9>(w0, w1, w2, w3), mk2(K2[2], K2[3]), Ao);

#define DOT_STEP(s_) do {                                                \
    const int r_ = rbase + (s_);                                         \
    const _Float16* rp_ = tile + r_ * ROWH;                              \
    const half8v w0 = *(const half8v*)(rp_ + (swzc(2 * tx + 0, r_) << 3)); \
    const half8v w1 = *(const half8v*)(rp_ + (swzc(2 * tx + 1, r_) << 3)); \
    const half8v w2 = *(const half8v*)(rp_ + (swzc(2 * tx + 2, r_) << 3)); \
    const half8v w3 = *(const half8v*)(rp_ + (swzc(2 * tx + 3, r_) << 3)); \
    const _Float16* kp_ = ckg + kbase + (s_) * 32;                       \
    const half8v K0 = *(const half8v*)(kp_);                             \
    const half8v K1 = *(const half8v*)(kp_ + 8);                         \
    const half4v K2 = *(const half4v*)(kp_ + 16);                        \
    OUTM(0, s0e, s0o, w0, w1, w2, w3, K0, K1, K2)                        \
    OUTM(1, s1e, s1o, w0, w1, w2, w3, K0, K1, K2)                        \
    OUTM(2, s2e, s2o, w0, w1, w2, w3, K0, K1, K2)                        \
    OUTM(3, s3e, s3o, w0, w1, w2, w3, K0, K1, K2)                        \
  } while (0)

    DOT_STEP(0);  DOT_STEP(1);  DOT_STEP(2);  DOT_STEP(3);  DOT_STEP(4);
    DOT_STEP(5);  DOT_STEP(6);  DOT_STEP(7);  DOT_STEP(8);  DOT_STEP(9);
    DOT_STEP(10); DOT_STEP(11); DOT_STEP(12); DOT_STEP(13); DOT_STEP(14);
    DOT_STEP(15); DOT_STEP(16); DOT_STEP(17); DOT_STEP(18); DOT_STEP(19);
#undef DOT_STEP
#undef OUTM

    const int oi = TH * by + ty;
    const int oj0 = TW * bxt + 4 * tx;
    float* orow = outg + ((size_t)bz * OHW + oi) * OHW + oj0;
    float* dump = dumpf + tid;   // scratch sink, never read
    const bool rowbad = (oi < 2) | (oi == 255);
    float* d0 = (rowbad | (oj0 + 0 < 2) | (oj0 + 0 == 255)) ? dump : (orow + 0);
    float* d1 = (rowbad | (oj0 + 1 < 2) | (oj0 + 1 == 255)) ? dump : (orow + 1);
    float* d2 = (rowbad | (oj0 + 2 < 2) | (oj0 + 2 == 255)) ? dump : (orow + 2);
    float* d3 = (rowbad | (oj0 + 3 < 2) | (oj0 + 3 == 255)) ? dump : (orow + 3);
    *d0 = s0e + s0o;
    *d1 = s1e + s1o;
    *d2 = s2e + s2o;
    *d3 = s3e + s3o;
  } else if (b < NEDGE) {
    // ================= edge path: rows/cols {0,1,255} minus corners =================
    _Float16* tileh = (_Float16*)smem;               // 20*528 halves = 21120 B
    float* ck   = (float*)(smem + 21120);            // 400 f32 -> 22720
    float* kva  = (float*)(smem + 22720);            // 180 f32 -> 23440
    float* mlds = (float*)(smem + 23440);            // 81 f32  -> 23764
    float* avs  = (float*)(smem + 23764);            // 12      -> 23812
    float* bvs  = (float*)(smem + 23812);            // 12      -> 23860

    const int e = b;
    const int bx = e & 1;
    const int t = e >> 1;
    const int segi6 = t % 6;
    const int bz = t / 6;
    const bool isRow = (segi6 < 3);
    const int segi = isRow ? segi6 : segi6 - 3;
    const int fixedo = (segi == 2) ? 255 : segi;
    const int chC = bz & 7;
    const int rv = rp[bz], cv = cp[bz];
    const int ri = rv >> 1, rf = rv & 1, ci = cv >> 1, cf = cv & 1;

    if (tid < 12) {
      float av = rf ? DEC12c[tid] : (tid == 6 ? 1.f : 0.f);
      if (isRow) {
        const int xi = (2 + 4 * fixedo - ri) - 6 + tid;
        if (xi < 0 || xi >= HH) av = 0.f;
      }
      avs[tid] = av;
    } else if (tid < 24) {
      const int q = tid - 12;
      float bv = cf ? DEC12c[q] : (q == 6 ? 1.f : 0.f);
      if (!isRow) {
        const int xj = (2 + 4 * fixedo - ci) - 6 + q;
        if (xj < 0 || xj >= HH) bv = 0.f;
      }
      bvs[q] = bv;
    } else if (tid < 105) {
      const int m = tid - 24; mlds[m] = mtfp[m * 8 + chC];
    }
    __syncthreads();

    for (int i = tid; i < 180; i += NTHREADS) {
      const int S = i / 9, v = i - S * 9;
      const int plo = (S - 8 > 0) ? S - 8 : 0, phi = (S < 11) ? S : 11;
      float s1 = 0.f;
      for (int p = plo; p <= phi; ++p) s1 += avs[p] * mlds[(S - p) * 9 + v];
      kva[i] = s1;
    }
    __syncthreads();
    for (int i = tid; i < 400; i += NTHREADS) {
      const int S = i / 20, T = i - S * 20;
      const int qlo = (T - 8 > 0) ? T - 8 : 0, qhi = (T < 11) ? T : 11;
      float s1 = 0.f;
      for (int q = qlo; q <= qhi; ++q) s1 += bvs[q] * kva[S * 9 + (T - q)];
      ck[i] = s1;
    }

    const float* src = inp + ((size_t)bz << 20);
    if (isRow) {
      // stage 20 rows x 528 cols as f16 (row-major coalesced)
      const int R0e = (2 + 4 * fixedo - ri) - 10;
      const int C0c = 512 * bx - 8 - ci;
      for (int i = tid; i < 20 * 66; i += NTHREADS) {
        const int rr = i / 66, jc = i - rr * 66;
        const float* grow = src + (clampi(R0e + rr) << 10);
        const int c0 = C0c + 8 * jc;
        float v[8];
        if (c0 >= 0 && c0 + 7 <= HH - 1) {
          __builtin_memcpy(v, grow + c0, 32);
        } else {
          #pragma unroll
          for (int k = 0; k < 8; ++k) v[k] = grow[clampi(c0 + k)];
        }
        _Float16 h[8];
        #pragma unroll
        for (int k = 0; k < 8; ++k) h[k] = (_Float16)v[k];
        __builtin_memcpy(tileh + rr * ESPAN + 8 * jc, h, 16);
      }
    } else {
      // stage transposed 20 cols x 528 rows as f16 — coalesced
      const int Cw0 = (2 + 4 * fixedo - ci) - 10;
      const int Rr0 = 512 * bx - 8 - ri;
      for (int i = tid; i < 20 * ESPAN; i += NTHREADS) {
        const int rr = i / 20, T = i - rr * 20;
        tileh[T * ESPAN + rr] =
            (_Float16)src[(clampi(Rr0 + rr) << 10) + clampi(Cw0 + T)];
      }
    }
    __syncthreads();

    if (tid < 128) {
      float acc = 0.f;
      for (int L = 0; L < 20; ++L) {
        const _Float16* wp = tileh + L * ESPAN + 4 * tid;
        #pragma unroll
        for (int j = 0; j < 5; ++j) {
          half4v h4;
          __builtin_memcpy(&h4, wp + 4 * j, 8);
          #pragma unroll
          for (int k = 0; k < 4; ++k) {
            const int ee = 4 * j + k;
            const float cv2 = isRow ? ck[L * 20 + ee] : ck[ee * 20 + L];
            acc += cv2 * (float)h4[k];
          }
        }
      }
      int oi, oj;
      if (isRow) { oi = fixedo; oj = 128 * bx + tid; }
      else       { oj = fixedo; oi = 128 * bx + tid; }
      const int ov = isRow ? oj : oi;
      if (ov != 0 && ov != 1 && ov != 255)
        outg[((size_t)bz * OHW + oi) * OHW + oj] = acc;
    }
  } else {
    // ================= corner path: 9 points/image =================
    float* mlds = (float*)smem;             // 81 f32
    float* avs  = (float*)(smem + 324);     // 12
    float* bvs  = (float*)(smem + 372);     // 12

    const int c = b - NEDGE;
    const int bi = c % 3;
    const int t = c / 3;
    const int bj = t % 3;
    const int bz = t / 3;
    const int oi = (bi == 2) ? 255 : bi;
    const int oj = (bj == 2) ? 255 : bj;
    const int chC = bz & 7;
    const int rv = rp[bz], cv = cp[bz];
    const int ri = rv >> 1, rf = rv & 1, ci = cv >> 1, cf = cv & 1;

    if (tid < 12)       avs[tid] = rf ? DEC12c[tid] : (tid == 6 ? 1.f : 0.f);
    else if (tid < 24)  bvs[tid - 12] = cf ? DEC12c[tid - 12] : (tid - 12 == 6 ? 1.f : 0.f);
    if (tid < 81) mlds[tid] = mtfp[tid * 8 + chC];
    __syncthreads();
    if (tid >= 64) return;

    const int Ri = 2 + 4 * oi - ri;
    const int Cj = 2 + 4 * oj - ci;
    const float* src = inp + ((size_t)bz << 20);

    float acc = 0.f;
    for (int pair = tid; pair < 144; pair += 64) {
      const int p = pair / 12, q = pair - 12 * (pair / 12);
      const int xi = Ri - 6 + p, xj = Cj - 6 + q;
      if (xi < 0 || xi >= HH || xj < 0 || xj >= HH) continue;
      const float ab = avs[p] * bvs[q];
      if (ab == 0.f) continue;
      float s = 0.f;
      #pragma unroll
      for (int u = 0; u < 9; ++u) {
        const float* grow = src + (clampi(xi - 4 + u) << 10);
        #pragma unroll
        for (int v = 0; v < 9; ++v) s += mlds[u * 9 + v] * grow[clampi(xj - 4 + v)];
      }
      acc += ab * s;
    }
    #pragma unroll
    for (int off = 32; off > 0; off >>= 1) acc += __shfl_down(acc, off);
    if (tid == 0) outg[((size_t)bz * OHW + oi) * OHW + oj] = acc;
  }
}

extern "C" void kernel_launch(void* const* d_in, const int* in_sizes, int n_in,
                              void* d_out, int out_size, void* d_ws, size_t ws_size,
                              hipStream_t stream) {
  const float* inp  = (const float*)d_in[0];
  const float* mtfp = (const float*)d_in[1];
  const int*   rp   = (const int*)d_in[2];
  const int*   cp   = (const int*)d_in[3];
  float* outg = (float*)d_out;
  _Float16* ckg = (_Float16*)d_ws;                  // 40 KB @ offset 0
  float* dumpf = (float*)((char*)d_ws + 49152);     // 1 KB dump sink

  hipLaunchKernelGGL(dgp_ckbuild, dim3(32), dim3(128), 0, stream, mtfp, rp, cp, ckg);
  hipLaunchKernelGGL(dgp_fused, dim3(NMAIN + NAUX), dim3(NTHREADS), 0, stream,
                     inp, mtfp, rp, cp, (const _Float16*)ckg, outg, dumpf);
}

// Round 22
// 89.779 us; speedup vs baseline: 1.2124x; 1.2124x over previous
//
#include <hip/hip_runtime.h>

typedef _Float16 half2v __attribute__((ext_vector_type(2)));
typedef _Float16 half4v __attribute__((ext_vector_type(4)));
typedef _Float16 half8v __attribute__((ext_vector_type(8)));

#define HH 1024
#define OHW 256
#define TH 16
#define TW 32
#define NR 80        // input-tile rows
#define NCH 18       // data chunks (8 halves) per row = 144 cols
#define ROWH 160     // padded row stride in halves (20 chunks)
#define NTHREADS 256
#define ESPAN 528    // edge strip length (halves/floats)

#define NMAIN 4096           // 8 x 16 x 32 main blocks
#define NEDGE 384            // 2 x 6 x 32
#define NCORN 288            // 3 x 3 x 32
#define NAUX  (NEDGE + NCORN)

#if defined(__has_builtin)
#  if __has_builtin(__builtin_amdgcn_fdot2)
#    define HAS_FDOT2 1
#  endif
#endif
#ifndef HAS_FDOT2
#  define HAS_FDOT2 0
#endif

__constant__ float DEC12c[12] = {
  -1.20162964e-04f,  1.615524292e-03f, -1.0385513306e-02f,  4.3619155884e-02f,
  -1.45397186478e-01f, 6.10668182370e-01f, 6.10668182370e-01f, -1.45397186478e-01f,
   4.3619155884e-02f, -1.0385513306e-02f,  1.615524292e-03f, -1.20162964e-04f
};

__device__ __forceinline__ int clampi(int v) { return v < 0 ? 0 : (v > HH - 1 ? HH - 1 : v); }

__device__ __forceinline__ int swzc(int c, int r) {
  return c ^ ((c >> 3) & 1) ^ ((r >> 2) & 3);
}

__device__ __forceinline__ half2v mk2(_Float16 a, _Float16 b) {
  half2v r; r.x = a; r.y = b; return r;
}

template<int J>   // J = half2 index 0..11 within 3 half8 regs
__device__ __forceinline__ half2v sel3(half8v a, half8v b, half8v c) {
  constexpr int V = J >> 2, E = J & 3;
  const half8v s = (V == 0) ? a : (V == 1) ? b : c;
  return mk2(s[2 * E], s[2 * E + 1]);
}
template<int E>
__device__ __forceinline__ half2v g2(half8v v) { return mk2(v[2 * E], v[2 * E + 1]); }

__device__ __forceinline__ float dot2acc(half2v w, half2v k, float acc) {
#if HAS_FDOT2
  return __builtin_amdgcn_fdot2(w, k, acc, false);
#else
  return acc + (float)w.x * (float)k.x + (float)w.y * (float)k.y;
#endif
}

// ---------------- dispatch 1: per-image combined 20x20 kernel -> d_ws (f16) ----------------
__global__ __launch_bounds__(128) void dgp_ckbuild(
    const float* __restrict__ mtfp, const int* __restrict__ rp,
    const int* __restrict__ cp, _Float16* __restrict__ ckg) {
  __shared__ float kva[180];
  __shared__ float mlds[81];
  __shared__ float avs[12], bvs[12];
  const int tid = threadIdx.x;
  const int bz = blockIdx.x;
  const int chC = bz & 7;
  const int rv = rp[bz], cv = cp[bz];
  const int rf = rv & 1, cf = cv & 1;

  if (tid < 12)       avs[tid] = rf ? DEC12c[tid] : (tid == 6 ? 1.f : 0.f);
  else if (tid < 24)  bvs[tid - 12] = cf ? DEC12c[tid - 12] : (tid - 12 == 6 ? 1.f : 0.f);
  else if (tid < 105) { const int m = tid - 24; mlds[m] = mtfp[m * 8 + chC]; }
  __syncthreads();

  for (int i = tid; i < 180; i += 128) {
    const int S = i / 9, v = i - S * 9;
    const int plo = (S - 8 > 0) ? S - 8 : 0, phi = (S < 11) ? S : 11;
    float s1 = 0.f;
    for (int p = plo; p <= phi; ++p) s1 += avs[p] * mlds[(S - p) * 9 + v];
    kva[i] = s1;
  }
  __syncthreads();

  half2v* out2 = (half2v*)ckg;
  for (int i = tid; i < 200; i += 128) {
    const int S = i / 10, m = i - S * 10;
    float s[2];
    #pragma unroll
    for (int h = 0; h < 2; ++h) {
      const int T = 2 * m + h;
      const int qlo = (T - 8 > 0) ? T - 8 : 0, qhi = (T < 11) ? T : 11;
      float acc = 0.f;
      for (int q = qlo; q <= qhi; ++q) acc += bvs[q] * kva[S * 9 + (T - q)];
      s[h] = acc;
    }
    out2[bz * 320 + S * 16 + m] = mk2((_Float16)s[0], (_Float16)s[1]);
  }
}

// ---------------- dispatch 2: fused edge + corner + main (aux FIRST) ----------------
// blocks [0,384): edge segments; [384,672): corners; [672,4768): main tiles.
// Disjoint write sets (main dump-redirects boundary; edge skips corners).
__global__ __launch_bounds__(NTHREADS) void dgp_fused(
    const float* __restrict__ inp, const float* __restrict__ mtfp,
    const int* __restrict__ rp, const int* __restrict__ cp,
    const _Float16* __restrict__ ckg, float* __restrict__ outg,
    float* __restrict__ dumpf) {
  __shared__ __align__(64) unsigned char smem[25600];
  const int tid = threadIdx.x;
  const int b = blockIdx.x;

  if (b >= NAUX) {
    // ================= main path =================
    _Float16* tile = (_Float16*)smem;   // 80*160 halves = 25600 B
    const int bm = b - NAUX;
    const int bxt = bm & 7, by = (bm >> 3) & 15, bz = bm >> 7;
    const int rv = rp[bz], cv = cp[bz];
    const int ri = rv >> 1, ci = cv >> 1;
    const int R0 = 4 * TH * by - 8 - ri;
    const int C0 = 4 * TW * bxt - 8 - ci;

    const float* src = inp + ((size_t)bz << 20);
    const bool interior = (R0 >= 0) && (R0 + NR <= HH) && (C0 >= 0) && (C0 + 8 * NCH <= HH);

#define CVW(rr, g, pa, pb) do {                                          \
      _Float16 h[8];                                                     \
      h[0]=(_Float16)pa.x; h[1]=(_Float16)pa.y; h[2]=(_Float16)pa.z;     \
      h[3]=(_Float16)pa.w; h[4]=(_Float16)pb.x; h[5]=(_Float16)pb.y;     \
      h[6]=(_Float16)pb.z; h[7]=(_Float16)pb.w;                          \
      __builtin_memcpy(tile + (rr) * ROWH + (swzc((g), (rr)) << 3), h, 16); \
    } while (0)

    if (interior) {
      // batched staging: 4 chunks' loads in flight, then 2.
      {
        const int i0 = tid, i1 = tid + 256, i2 = tid + 512, i3 = tid + 768;
        const int rr0 = i0 / 18, g0 = i0 - 18 * rr0;
        const int rr1 = i1 / 18, g1 = i1 - 18 * rr1;
        const int rr2 = i2 / 18, g2c = i2 - 18 * rr2;
        const int rr3 = i3 / 18, g3 = i3 - 18 * rr3;
        const float* a0 = src + ((R0 + rr0) << 10) + C0 + 8 * g0;
        const float* a1 = src + ((R0 + rr1) << 10) + C0 + 8 * g1;
        const float* a2 = src + ((R0 + rr2) << 10) + C0 + 8 * g2c;
        const float* a3 = src + ((R0 + rr3) << 10) + C0 + 8 * g3;
        const float4 p0a = *(const float4*)a0, p0b = *(const float4*)(a0 + 4);
        const float4 p1a = *(const float4*)a1, p1b = *(const float4*)(a1 + 4);
        const float4 p2a = *(const float4*)a2, p2b = *(const float4*)(a2 + 4);
        const float4 p3a = *(const float4*)a3, p3b = *(const float4*)(a3 + 4);
        CVW(rr0, g0, p0a, p0b);
        CVW(rr1, g1, p1a, p1b);
        CVW(rr2, g2c, p2a, p2b);
        CVW(rr3, g3, p3a, p3b);
      }
      {
        const int i4 = tid + 1024;
        const int i5 = tid + 1280;          // valid only for tid < 160
        const int rr4 = i4 / 18, g4 = i4 - 18 * rr4;
        const int rr5 = i5 / 18, g5 = i5 - 18 * rr5;
        const float* a4 = src + ((R0 + rr4) << 10) + C0 + 8 * g4;
        const float4 p4a = *(const float4*)a4, p4b = *(const float4*)(a4 + 4);
        float4 p5a, p5b;
        if (tid < 160) {
          const float* a5 = src + ((R0 + rr5) << 10) + C0 + 8 * g5;
          p5a = *(const float4*)a5; p5b = *(const float4*)(a5 + 4);
        }
        CVW(rr4, g4, p4a, p4b);
        if (tid < 160) CVW(rr5, g5, p5a, p5b);
      }
    } else {
      for (int idx = tid; idx < NR * NCH; idx += NTHREADS) {
        const int rr = idx / 18, g = idx - 18 * rr;
        const float* grow = src + (clampi(R0 + rr) << 10);
        const int c0 = C0 + 8 * g;
        float v[8];
        if (c0 >= 0 && c0 + 7 <= HH - 1) {
          __builtin_memcpy(v, grow + c0, 32);
        } else {
          #pragma unroll
          for (int i = 0; i < 8; ++i) v[i] = grow[clampi(c0 + i)];
        }
        _Float16 h[8];
        #pragma unroll
        for (int i = 0; i < 8; ++i) h[i] = (_Float16)v[i];
        __builtin_memcpy(tile + rr * ROWH + (swzc(g, rr) << 3), h, 16);
      }
    }
#undef CVW
    __syncthreads();

    const int ty = tid >> 4;
    const int tx = tid & 15;
    const int rbase = 4 * ty;
    const size_t kbase = (size_t)bz * 640;

    float a0e = 0.f, a0o = 0.f, a1e = 0.f, a1o = 0.f;

#define DOT_STEP(s_) do {                                                \
    const int r_ = rbase + (s_);                                         \
    const _Float16* rp_ = tile + r_ * ROWH;                              \
    const half8v w0 = *(const half8v*)(rp_ + (swzc(tx + 0, r_) << 3));   \
    const half8v w1 = *(const half8v*)(rp_ + (swzc(tx + 1, r_) << 3));   \
    const half8v w2 = *(const half8v*)(rp_ + (swzc(tx + 2, r_) << 3));   \
    const _Float16* kp_ = ckg + kbase + (s_) * 32;                       \
    const half8v K0 = *(const half8v*)(kp_);                             \
    const half8v K1 = *(const half8v*)(kp_ + 8);                         \
    const half4v K2 = *(const half4v*)(kp_ + 16);                        \
    a0e = dot2acc(sel3<0>(w0, w1, w2), g2<0>(K0), a0e);                  \
    a0o = dot2acc(sel3<1>(w0, w1, w2), g2<1>(K0), a0o);                  \
    a0e = dot2acc(sel3<2>(w0, w1, w2), g2<2>(K0), a0e);                  \
    a0o = dot2acc(sel3<3>(w0, w1, w2), g2<3>(K0), a0o);                  \
    a0e = dot2acc(sel3<4>(w0, w1, w2), g2<0>(K1), a0e);                  \
    a0o = dot2acc(sel3<5>(w0, w1, w2), g2<1>(K1), a0o);                  \
    a0e = dot2acc(sel3<6>(w0, w1, w2), g2<2>(K1), a0e);                  \
    a0o = dot2acc(sel3<7>(w0, w1, w2), g2<3>(K1), a0o);                  \
    a0e = dot2acc(sel3<8>(w0, w1, w2), mk2(K2[0], K2[1]), a0e);          \
    a0o = dot2acc(sel3<9>(w0, w1, w2), mk2(K2[2], K2[3]), a0o);          \
    a1e = dot2acc(sel3<2>(w0, w1, w2), g2<0>(K0), a1e);                  \
    a1o = dot2acc(sel3<3>(w0, w1, w2), g2<1>(K0), a1o);                  \
    a1e = dot2acc(sel3<4>(w0, w1, w2), g2<2>(K0), a1e);                  \
    a1o = dot2acc(sel3<5>(w0, w1, w2), g2<3>(K0), a1o);                  \
    a1e = dot2acc(sel3<6>(w0, w1, w2), g2<0>(K1), a1e);                  \
    a1o = dot2acc(sel3<7>(w0, w1, w2), g2<1>(K1), a1o);                  \
    a1e = dot2acc(sel3<8>(w0, w1, w2), g2<2>(K1), a1e);                  \
    a1o = dot2acc(sel3<9>(w0, w1, w2), g2<3>(K1), a1o);                  \
    a1e = dot2acc(sel3<10>(w0, w1, w2), mk2(K2[0], K2[1]), a1e);         \
    a1o = dot2acc(sel3<11>(w0, w1, w2), mk2(K2[2], K2[3]), a1o);         \
  } while (0)

    DOT_STEP(0);  DOT_STEP(1);  DOT_STEP(2);  DOT_STEP(3);  DOT_STEP(4);
    DOT_STEP(5);  DOT_STEP(6);  DOT_STEP(7);  DOT_STEP(8);  DOT_STEP(9);
    DOT_STEP(10); DOT_STEP(11); DOT_STEP(12); DOT_STEP(13); DOT_STEP(14);
    DOT_STEP(15); DOT_STEP(16); DOT_STEP(17); DOT_STEP(18); DOT_STEP(19);
#undef DOT_STEP

    const int oi = TH * by + ty;
    const int oj0 = TW * bxt + 2 * tx;
    const int oj1 = oj0 + 1;
    float* orow = outg + ((size_t)bz * OHW + oi) * OHW + oj0;
    float* dump = dumpf + tid;   // scratch sink, never read
    const bool rowbad = (oi < 2) | (oi == 255);
    float* d0 = (rowbad | (oj0 < 2) | (oj0 == 255)) ? dump : orow;
    float* d1 = (rowbad | (oj1 < 2) | (oj1 == 255)) ? dump : (orow + 1);
    *d0 = a0e + a0o;
    *d1 = a1e + a1o;
  } else if (b < NEDGE) {
    // ================= edge path: rows/cols {0,1,255} minus corners =================
    _Float16* tileh = (_Float16*)smem;               // 20*528 halves = 21120 B
    float* ck   = (float*)(smem + 21120);            // 400 f32 -> 22720
    float* kva  = (float*)(smem + 22720);            // 180 f32 -> 23440
    float* mlds = (float*)(smem + 23440);            // 81 f32  -> 23764
    float* avs  = (float*)(smem + 23764);            // 12      -> 23812
    float* bvs  = (float*)(smem + 23812);            // 12      -> 23860

    const int e = b;
    const int bx = e & 1;
    const int t = e >> 1;
    const int segi6 = t % 6;
    const int bz = t / 6;
    const bool isRow = (segi6 < 3);
    const int segi = isRow ? segi6 : segi6 - 3;
    const int fixedo = (segi == 2) ? 255 : segi;
    const int chC = bz & 7;
    const int rv = rp[bz], cv = cp[bz];
    const int ri = rv >> 1, rf = rv & 1, ci = cv >> 1, cf = cv & 1;

    if (tid < 12) {
      float av = rf ? DEC12c[tid] : (tid == 6 ? 1.f : 0.f);
      if (isRow) {
        const int xi = (2 + 4 * fixedo - ri) - 6 + tid;
        if (xi < 0 || xi >= HH) av = 0.f;
      }
      avs[tid] = av;
    } else if (tid < 24) {
      const int q = tid - 12;
      float bv = cf ? DEC12c[q] : (q == 6 ? 1.f : 0.f);
      if (!isRow) {
        const int xj = (2 + 4 * fixedo - ci) - 6 + q;
        if (xj < 0 || xj >= HH) bv = 0.f;
      }
      bvs[q] = bv;
    } else if (tid < 105) {
      const int m = tid - 24; mlds[m] = mtfp[m * 8 + chC];
    }
    __syncthreads();

    for (int i = tid; i < 180; i += NTHREADS) {
      const int S = i / 9, v = i - S * 9;
      const int plo = (S - 8 > 0) ? S - 8 : 0, phi = (S < 11) ? S : 11;
      float s1 = 0.f;
      for (int p = plo; p <= phi; ++p) s1 += avs[p] * mlds[(S - p) * 9 + v];
      kva[i] = s1;
    }
    __syncthreads();
    for (int i = tid; i < 400; i += NTHREADS) {
      const int S = i / 20, T = i - S * 20;
      const int qlo = (T - 8 > 0) ? T - 8 : 0, qhi = (T < 11) ? T : 11;
      float s1 = 0.f;
      for (int q = qlo; q <= qhi; ++q) s1 += bvs[q] * kva[S * 9 + (T - q)];
      ck[i] = s1;
    }

    const float* src = inp + ((size_t)bz << 20);
    if (isRow) {
      // stage 20 rows x 528 cols as f16 (row-major coalesced)
      const int R0e = (2 + 4 * fixedo - ri) - 10;
      const int C0c = 512 * bx - 8 - ci;
      for (int i = tid; i < 20 * 66; i += NTHREADS) {
        const int rr = i / 66, jc = i - rr * 66;
        const float* grow = src + (clampi(R0e + rr) << 10);
        const int c0 = C0c + 8 * jc;
        float v[8];
        if (c0 >= 0 && c0 + 7 <= HH - 1) {
          __builtin_memcpy(v, grow + c0, 32);
        } else {
          #pragma unroll
          for (int k = 0; k < 8; ++k) v[k] = grow[clampi(c0 + k)];
        }
        _Float16 h[8];
        #pragma unroll
        for (int k = 0; k < 8; ++k) h[k] = (_Float16)v[k];
        __builtin_memcpy(tileh + rr * ESPAN + 8 * jc, h, 16);
      }
    } else {
      // stage transposed 20 cols x 528 rows as f16 — coalesced
      const int Cw0 = (2 + 4 * fixedo - ci) - 10;
      const int Rr0 = 512 * bx - 8 - ri;
      for (int i = tid; i < 20 * ESPAN; i += NTHREADS) {
        const int rr = i / 20, T = i - rr * 20;
        tileh[T * ESPAN + rr] =
            (_Float16)src[(clampi(Rr0 + rr) << 10) + clampi(Cw0 + T)];
      }
    }
    __syncthreads();

    if (tid < 128) {
      float acc = 0.f;
      for (int L = 0; L < 20; ++L) {
        const _Float16* wp = tileh + L * ESPAN + 4 * tid;
        #pragma unroll
        for (int j = 0; j < 5; ++j) {
          half4v h4;
          __builtin_memcpy(&h4, wp + 4 * j, 8);
          #pragma unroll
          for (int k = 0; k < 4; ++k) {
            const int ee = 4 * j + k;
            const float cv2 = isRow ? ck[L * 20 + ee] : ck[ee * 20 + L];
            acc += cv2 * (float)h4[k];
          }
        }
      }
      int oi, oj;
      if (isRow) { oi = fixedo; oj = 128 * bx + tid; }
      else       { oj = fixedo; oi = 128 * bx + tid; }
      const int ov = isRow ? oj : oi;
      if (ov != 0 && ov != 1 && ov != 255)
        outg[((size_t)bz * OHW + oi) * OHW + oj] = acc;
    }
  } else {
    // ================= corner path: 9 points/image =================
    float* mlds = (float*)smem;             // 81 f32
    float* avs  = (float*)(smem + 324);     // 12
    float* bvs  = (float*)(smem + 372);     // 12

    const int c = b - NEDGE;
    const int bi = c % 3;
    const int t = c / 3;
    const int bj = t % 3;
    const int bz = t / 3;
    const int oi = (bi == 2) ? 255 : bi;
    const int oj = (bj == 2) ? 255 : bj;
    const int chC = bz & 7;
    const int rv = rp[bz], cv = cp[bz];
    const int ri = rv >> 1, rf = rv & 1, ci = cv >> 1, cf = cv & 1;

    if (tid < 12)       avs[tid] = rf ? DEC12c[tid] : (tid == 6 ? 1.f : 0.f);
    else if (tid < 24)  bvs[tid - 12] = cf ? DEC12c[tid - 12] : (tid - 12 == 6 ? 1.f : 0.f);
    if (tid < 81) mlds[tid] = mtfp[tid * 8 + chC];
    __syncthreads();
    if (tid >= 64) return;

    const int Ri = 2 + 4 * oi - ri;
    const int Cj = 2 + 4 * oj - ci;
    const float* src = inp + ((size_t)bz << 20);

    float acc = 0.f;
    for (int pair = tid; pair < 144; pair += 64) {
      const int p = pair / 12, q = pair - 12 * (pair / 12);
      const int xi = Ri - 6 + p, xj = Cj - 6 + q;
      if (xi < 0 || xi >= HH || xj < 0 || xj >= HH) continue;
      const float ab = avs[p] * bvs[q];
      if (ab == 0.f) continue;
      float s = 0.f;
      #pragma unroll
      for (int u = 0; u < 9; ++u) {
        const float* grow = src + (clampi(xi - 4 + u) << 10);
        #pragma unroll
        for (int v = 0; v < 9; ++v) s += mlds[u * 9 + v] * grow[clampi(xj - 4 + v)];
      }
      acc += ab * s;
    }
    #pragma unroll
    for (int off = 32; off > 0; off >>= 1) acc += __shfl_down(acc, off);
    if (tid == 0) outg[((size_t)bz * OHW + oi) * OHW + oj] = acc;
  }
}

extern "C" void kernel_launch(void* const* d_in, const int* in_sizes, int n_in,
                              void* d_out, int out_size, void* d_ws, size_t ws_size,
                              hipStream_t stream) {
  const float* inp  = (const float*)d_in[0];
  const float* mtfp = (const float*)d_in[1];
  const int*   rp   = (const int*)d_in[2];
  const int*   cp   = (const int*)d_in[3];
  float* outg = (float*)d_out;
  _Float16* ckg = (_Float16*)d_ws;                  // 40 KB @ offset 0
  float* dumpf = (float*)((char*)d_ws + 49152);     // 1 KB dump sink

  hipLaunchKernelGGL(dgp_ckbuild, dim3(32), dim3(128), 0, stream, mtfp, rp, cp, ckg);
  hipLaunchKernelGGL(dgp_fused, dim3(NMAIN + NAUX), dim3(NTHREADS), 0, stream,
                     inp, mtfp, rp, cp, (const _Float16*)ckg, outg, dumpf);
}